// Round 13
// baseline (677.783 us; speedup 1.0000x reference)
//
#include <hip/hip_runtime.h>
#include <hip/hip_bf16.h>
#include <cstddef>
#include <cstdint>

#define N_NODES 100000
#define N_EDGES 1600000
#define NPASS 2

typedef __attribute__((ext_vector_type(8))) short bf16x8;
typedef __attribute__((ext_vector_type(4))) float f32x4;
typedef __attribute__((ext_vector_type(2))) _Float16 half2_t;
typedef __attribute__((ext_vector_type(4))) _Float16 half4_t;
typedef __attribute__((ext_vector_type(8))) _Float16 half8_t;

__device__ inline unsigned short f2bf(float x) {
    unsigned int u = __float_as_uint(x);
    unsigned int r = (u + 0x7fffu + ((u >> 16) & 1u)) >> 16;
    return (unsigned short)r;
}
__device__ inline float bf2f(unsigned short b) {
    return __uint_as_float((unsigned int)b << 16);
}
__device__ inline unsigned short f2h_bits(float x) {
    _Float16 h = (_Float16)x;
    return __builtin_bit_cast(unsigned short, h);
}

template <int VV> struct hvsel;
template <> struct hvsel<4> { typedef half4_t T; };
template <> struct hvsel<8> { typedef half8_t T; };

// ---------------------------------------------------------------- CSR build
__global__ void hist_kernel(const int* __restrict__ dst, int* __restrict__ deg) {
    int e = blockIdx.x * 256 + threadIdx.x;
    if (e < N_EDGES) atomicAdd(&deg[dst[e]], 1);
}

__global__ void scan_block_kernel(const int* __restrict__ deg, int* __restrict__ rowptr,
                                  int* __restrict__ bsum) {
    __shared__ int s[256];
    int t = threadIdx.x;
    int base = blockIdx.x * 1024 + t * 4;
    int v[4]; int sum = 0;
#pragma unroll
    for (int j = 0; j < 4; ++j) { v[j] = (base + j < N_NODES) ? deg[base + j] : 0; sum += v[j]; }
    s[t] = sum; __syncthreads();
    for (int off = 1; off < 256; off <<= 1) {
        int x = (t >= off) ? s[t - off] : 0;
        __syncthreads();
        s[t] += x;
        __syncthreads();
    }
    int excl = (t > 0) ? s[t - 1] : 0;
    if (t == 255) bsum[blockIdx.x] = s[255];
    int run = excl;
#pragma unroll
    for (int j = 0; j < 4; ++j) { if (base + j < N_NODES) rowptr[base + j] = run; run += v[j]; }
}

__global__ void scan_bsum_kernel(int* bsum, int nb) {
    __shared__ int s[128];
    int t = threadIdx.x;
    int v = (t < nb) ? bsum[t] : 0;
    s[t] = v; __syncthreads();
    for (int off = 1; off < 128; off <<= 1) {
        int x = (t >= off) ? s[t - off] : 0;
        __syncthreads();
        s[t] += x;
        __syncthreads();
    }
    if (t < nb) bsum[t] = (t > 0) ? s[t - 1] : 0;
}

__global__ void scan_add_kernel(int* __restrict__ rowptr, const int* __restrict__ bsum) {
    int i = blockIdx.x * 256 + threadIdx.x;
    if (i < N_NODES) rowptr[i] += bsum[i >> 10];
    if (i == 0) rowptr[N_NODES] = N_EDGES;
}

// Bucketed scatter: write window (csr slab + fill slice) is L2-resident per pass.
__global__ __launch_bounds__(256) void scatter_pass_kernel(
    const int* __restrict__ src, const int* __restrict__ dst,
    const int* __restrict__ rowptr, int* __restrict__ fill,
    int* __restrict__ csr_src, int lo, int hi) {
    int e = blockIdx.x * 256 + threadIdx.x;
    if (e >= N_EDGES) return;
    int d = dst[e];
    if (d >= lo && d < hi) {
        int pos = rowptr[d] + atomicAdd(&fill[d], 1);
        csr_src[pos] = src[e];
    }
}

// ---------------------------------------------------------------- W converts (all 3, one launch)
__global__ __launch_bounds__(256) void convert_w_all_kernel(
    const float* __restrict__ W0, const float* __restrict__ W1, const float* __restrict__ W2,
    unsigned short* __restrict__ Wt0h, unsigned short* __restrict__ Wt0l,
    unsigned short* __restrict__ Wt1h, unsigned short* __restrict__ Wt1l,
    unsigned short* __restrict__ Wt2h, unsigned short* __restrict__ Wt2l) {
    int t = blockIdx.x * 256 + threadIdx.x;
    const float* W; unsigned short* Wh; unsigned short* Wl; int Ncols; int i;
    if (t < 16384)      { W = W0; Wh = Wt0h; Wl = Wt0l; Ncols = 128; i = t; }
    else if (t < 32768) { W = W1; Wh = Wt1h; Wl = Wt1l; Ncols = 128; i = t - 16384; }
    else                { W = W2; Wh = Wt2h; Wl = Wt2l; Ncols = 256; i = t - 32768; }
    int n = i >> 7, k = i & 127;
    float x = W[(size_t)k * Ncols + n];
    unsigned short h = f2bf(x);
    unsigned short l = f2bf(x - bf2f(h));
    Wh[i] = h;
    Wl[i] = l;
}

// ---------------------------------------------------------------- MFMA split-bf16 GEMM
// FP32IN: stage raw fp32 X, split to bf16 hi/lo during staging (layer 0).
// Fused epilogue: el/er from fp32 acc (16-lane butterfly) + fp16 h via LDS repack.
template <int DHEAD, bool FP32IN>
__global__ __launch_bounds__(256) void mfma_gemm_kernel(
    const unsigned short* __restrict__ Xhi, const unsigned short* __restrict__ Xlo,
    const float* __restrict__ Xf,
    const unsigned short* __restrict__ Wth, const unsigned short* __restrict__ Wtl,
    float* __restrict__ el, float* __restrict__ er, _Float16* __restrict__ Hh,
    int M, int ldH, const float* __restrict__ alv, const float* __restrict__ arv) {
    __shared__ unsigned short AH[128 * 136];
    __shared__ unsigned short AL[128 * 136];
    const int tid = threadIdx.x;
    const int wave = tid >> 6, lane = tid & 63;
    const int r = lane & 15, kg = lane >> 4;
    const int row0 = blockIdx.x * 128;
    const int col0 = blockIdx.y * 128;

    if constexpr (FP32IN) {
#pragma unroll
        for (int i = 0; i < 16; ++i) {
            int idx = i * 256 + tid;
            int rr = idx >> 5;
            int u = idx & 31;
            int grow = row0 + rr;
            if (grow > M - 1) grow = M - 1;
            float4 v = *reinterpret_cast<const float4*>(Xf + (size_t)grow * 128 + u * 4);
            unsigned short h0 = f2bf(v.x), h1 = f2bf(v.y), h2 = f2bf(v.z), h3 = f2bf(v.w);
            unsigned short l0 = f2bf(v.x - bf2f(h0)), l1 = f2bf(v.y - bf2f(h1));
            unsigned short l2 = f2bf(v.z - bf2f(h2)), l3 = f2bf(v.w - bf2f(h3));
            unsigned int* hp = reinterpret_cast<unsigned int*>(&AH[rr * 136 + u * 4]);
            hp[0] = (unsigned int)h0 | ((unsigned int)h1 << 16);
            hp[1] = (unsigned int)h2 | ((unsigned int)h3 << 16);
            unsigned int* lp = reinterpret_cast<unsigned int*>(&AL[rr * 136 + u * 4]);
            lp[0] = (unsigned int)l0 | ((unsigned int)l1 << 16);
            lp[1] = (unsigned int)l2 | ((unsigned int)l3 << 16);
        }
    } else {
#pragma unroll
        for (int i = 0; i < 16; ++i) {
            int sa = i * 256 + tid;
            int a = sa >> 11;
            int s = sa & 2047;
            int rr = s >> 4;
            int u = s & 15;
            const unsigned short* srcp = (a ? Xlo : Xhi) + (size_t)(row0 + rr) * 128 + u * 8;
            unsigned short* dstp = (a ? AL : AH) + rr * 136 + u * 8;
            *reinterpret_cast<uint4*>(dstp) = *reinterpret_cast<const uint4*>(srcp);
        }
    }
    __syncthreads();

    f32x4 acc[2][8];
#pragma unroll
    for (int rt = 0; rt < 2; ++rt)
#pragma unroll
        for (int ct = 0; ct < 8; ++ct)
            acc[rt][ct] = (f32x4){0.f, 0.f, 0.f, 0.f};

#pragma unroll
    for (int ks = 0; ks < 4; ++ks) {
        bf16x8 bh[8], bl[8];
#pragma unroll
        for (int ct = 0; ct < 8; ++ct) {
            size_t off = (size_t)(col0 + ct * 16 + r) * 128 + ks * 32 + kg * 8;
            bh[ct] = *reinterpret_cast<const bf16x8*>(Wth + off);
            bl[ct] = *reinterpret_cast<const bf16x8*>(Wtl + off);
        }
#pragma unroll
        for (int rt = 0; rt < 2; ++rt) {
            int lrow = wave * 32 + rt * 16 + r;
            bf16x8 ah = *reinterpret_cast<const bf16x8*>(&AH[lrow * 136 + ks * 32 + kg * 8]);
            bf16x8 al8 = *reinterpret_cast<const bf16x8*>(&AL[lrow * 136 + ks * 32 + kg * 8]);
#pragma unroll
            for (int ct = 0; ct < 8; ++ct) {
                acc[rt][ct] = __builtin_amdgcn_mfma_f32_16x16x32_bf16(ah, bh[ct], acc[rt][ct], 0, 0, 0);
                acc[rt][ct] = __builtin_amdgcn_mfma_f32_16x16x32_bf16(al8, bh[ct], acc[rt][ct], 0, 0, 0);
                acc[rt][ct] = __builtin_amdgcn_mfma_f32_16x16x32_bf16(ah, bl[ct], acc[rt][ct], 0, 0, 0);
            }
        }
    }

    // ---- epilogue 1: el/er
    constexpr int CTH = DHEAD / 16;
    constexpr int HB = 8 / CTH;
    float als[8], ars[8];
#pragma unroll
    for (int ct = 0; ct < 8; ++ct) {
        als[ct] = alv[col0 + ct * 16 + r];
        ars[ct] = arv[col0 + ct * 16 + r];
    }
    f32x4 pel[2][HB], per_[2][HB];
#pragma unroll
    for (int rt = 0; rt < 2; ++rt)
#pragma unroll
        for (int hl = 0; hl < HB; ++hl) {
            pel[rt][hl] = (f32x4){0.f, 0.f, 0.f, 0.f};
            per_[rt][hl] = (f32x4){0.f, 0.f, 0.f, 0.f};
        }
#pragma unroll
    for (int rt = 0; rt < 2; ++rt)
#pragma unroll
        for (int ct = 0; ct < 8; ++ct) {
            pel[rt][ct / CTH] += acc[rt][ct] * als[ct];
            per_[rt][ct / CTH] += acc[rt][ct] * ars[ct];
        }
#pragma unroll
    for (int off = 1; off < 16; off <<= 1) {
#pragma unroll
        for (int rt = 0; rt < 2; ++rt)
#pragma unroll
            for (int hl = 0; hl < HB; ++hl)
#pragma unroll
                for (int j = 0; j < 4; ++j) {
                    pel[rt][hl][j] += __shfl_xor(pel[rt][hl][j], off);
                    per_[rt][hl][j] += __shfl_xor(per_[rt][hl][j], off);
                }
    }
#pragma unroll
    for (int hl = 0; hl < HB; ++hl) {
        if (r == hl) {
            int hg = col0 / DHEAD + hl;
#pragma unroll
            for (int rt = 0; rt < 2; ++rt)
#pragma unroll
                for (int j = 0; j < 4; ++j) {
                    int grow = row0 + wave * 32 + rt * 16 + kg * 4 + j;
                    if (grow < M) {
                        el[(size_t)grow * 4 + hg] = pel[rt][hl][j];
                        er[(size_t)grow * 4 + hg] = per_[rt][hl][j];
                    }
                }
        }
    }

    // ---- epilogue 2: fp16 h via LDS repack
    __syncthreads();
#pragma unroll
    for (int rt = 0; rt < 2; ++rt)
#pragma unroll
        for (int ct = 0; ct < 8; ++ct)
#pragma unroll
            for (int j = 0; j < 4; ++j) {
                int lrow = wave * 32 + rt * 16 + kg * 4 + j;
                AH[lrow * 136 + ct * 16 + r] = f2h_bits(acc[rt][ct][j]);
            }
    __syncthreads();
#pragma unroll
    for (int it = 0; it < 8; ++it) {
        int idx = it * 256 + tid;
        int rr = idx >> 4;
        int c8 = idx & 15;
        int grow = row0 + rr;
        if (grow < M)
            *reinterpret_cast<uint4*>(Hh + (size_t)grow * ldH + col0 + c8 * 8) =
                *reinterpret_cast<const uint4*>(&AH[rr * 136 + c8 * 8]);
    }
}

// ---------------------------------------------------------------- fused softmax+gather
// TWO NODES PER WAVE (half-wave = one node, 32 lanes). Lane hl owns V=F/32
// consecutive feats (8B half4 for F=128, 16B half8 for F=256); head hh=hl>>3.
// Latency pipelining: quad-0 feature loads issue BEFORE the el/exp/LDS score
// phase (they depend only on csr_src), and quad q+1 is prefetched during quad
// q's FMAs. wsh accesses are volatile: preserves the DS write->read program
// order (same-wave DS executes in issue order) WITHOUT fencing the global
// feature loads the way r10's blanket asm-memory fences did.
// Summation order is BIT-IDENTICAL to r12: chain = e mod 4 for full quads,
// tail singles -> ac0, den group-of-4 tree, ((ac0+ac1)+(ac2+ac3))*inv+bias.
// MODE 0: elu -> bf16 hi/lo [N,F].  MODE 1: head-mean -> out[N,F/4] fp32.
template <int F, int MODE>
__global__ __launch_bounds__(256) void sgather2_kernel(
    const _Float16* __restrict__ hfeat, const float* __restrict__ el,
    const float* __restrict__ er, const int* __restrict__ rowptr,
    const int* __restrict__ csr_src, const float* __restrict__ bias,
    float* __restrict__ out, unsigned short* __restrict__ ohi,
    unsigned short* __restrict__ olo) {
    constexpr int V = F / 32;             // 4 (F=128) or 8 (F=256)
    constexpr int D = F / 4;
    typedef typename hvsel<V>::T HV;
    __shared__ float wsh[4][2][128];
    int wv = threadIdx.x >> 6;
    int lane = threadIdx.x & 63;
    int hw = lane >> 5;                   // which half-wave (node select)
    int hl = lane & 31;                   // lane within half-wave
    int wid = blockIdx.x * 8 + (threadIdx.x >> 5);
    if (wid >= N_NODES) return;
    int row0 = rowptr[wid], row1 = rowptr[wid + 1];
    int f0 = hl * V;
    int hh = hl >> 3;                     // = f0 / D for both F=128,256
    float4 ern = *reinterpret_cast<const float4*>(er + (size_t)wid * 4);

    float ac0[V], ac1[V], ac2[V], ac3[V];
#pragma unroll
    for (int v = 0; v < V; ++v) { ac0[v] = 0.f; ac1[v] = 0.f; ac2[v] = 0.f; ac3[v] = 0.f; }
    float den = 0.f;
    volatile float* ws = &wsh[wv][hw][0];

    for (int base = row0; base < row1; base += 32) {
        int i = base + hl;
        int sv = (i < row1) ? csr_src[i] : 0;
        int cnt = min(32, row1 - base);

        // ---- quad-0 prefetch (independent of el) — overlaps the score phase
        HV a, b, c, d;
        if (cnt >= 4) {
            int s0 = __shfl(sv, 0, 32), s1 = __shfl(sv, 1, 32);
            int s2 = __shfl(sv, 2, 32), s3 = __shfl(sv, 3, 32);
            a = *reinterpret_cast<const HV*>(hfeat + (size_t)s0 * F + f0);
            b = *reinterpret_cast<const HV*>(hfeat + (size_t)s1 * F + f0);
            c = *reinterpret_cast<const HV*>(hfeat + (size_t)s2 * F + f0);
            d = *reinterpret_cast<const HV*>(hfeat + (size_t)s3 * F + f0);
        }

        // ---- score phase: this lane's edge, all 4 heads
        float4 e4 = *reinterpret_cast<const float4*>(el + (size_t)sv * 4);
        float4 es;
        es.x = e4.x + ern.x; es.x = es.x > 0.f ? es.x : 0.2f * es.x; es.x = __expf(es.x);
        es.y = e4.y + ern.y; es.y = es.y > 0.f ? es.y : 0.2f * es.y; es.y = __expf(es.y);
        es.z = e4.z + ern.z; es.z = es.z > 0.f ? es.z : 0.2f * es.z; es.z = __expf(es.z);
        es.w = e4.w + ern.w; es.w = es.w > 0.f ? es.w : 0.2f * es.w; es.w = __expf(es.w);
        ws[hl * 4 + 0] = es.x; ws[hl * 4 + 1] = es.y;
        ws[hl * 4 + 2] = es.z; ws[hl * 4 + 3] = es.w;   // volatile DS: ordered vs reads

        int j = 0;
        for (; j + 4 <= cnt; j += 4) {
            HV a2, b2, c2, d2;
            bool more = (j + 8 <= cnt);
            if (more) {
                int t0 = __shfl(sv, j + 4, 32), t1 = __shfl(sv, j + 5, 32);
                int t2 = __shfl(sv, j + 6, 32), t3 = __shfl(sv, j + 7, 32);
                a2 = *reinterpret_cast<const HV*>(hfeat + (size_t)t0 * F + f0);
                b2 = *reinterpret_cast<const HV*>(hfeat + (size_t)t1 * F + f0);
                c2 = *reinterpret_cast<const HV*>(hfeat + (size_t)t2 * F + f0);
                d2 = *reinterpret_cast<const HV*>(hfeat + (size_t)t3 * F + f0);
            }
            float w0 = ws[(j + 0) * 4 + hh], w1 = ws[(j + 1) * 4 + hh];
            float w2 = ws[(j + 2) * 4 + hh], w3 = ws[(j + 3) * 4 + hh];
            den += (w0 + w1) + (w2 + w3);
#pragma unroll
            for (int v = 0; v < V; ++v) {
                ac0[v] = fmaf(w0, (float)a[v], ac0[v]);
                ac1[v] = fmaf(w1, (float)b[v], ac1[v]);
                ac2[v] = fmaf(w2, (float)c[v], ac2[v]);
                ac3[v] = fmaf(w3, (float)d[v], ac3[v]);
            }
            if (more) { a = a2; b = b2; c = c2; d = d2; }
        }
        for (; j < cnt; ++j) {
            int s0 = __shfl(sv, j, 32);
            float w0 = ws[j * 4 + hh];
            den += w0;
            HV t = *reinterpret_cast<const HV*>(hfeat + (size_t)s0 * F + f0);
#pragma unroll
            for (int v = 0; v < V; ++v) ac0[v] = fmaf(w0, (float)t[v], ac0[v]);
        }
    }

    float inv = den > 0.f ? 1.f / den : 0.f;
    float val[V];
#pragma unroll
    for (int v = 0; v < V; ++v)
        val[v] = ((ac0[v] + ac1[v]) + (ac2[v] + ac3[v])) * inv + bias[f0 + v];

    if (MODE == 0) {
#pragma unroll
        for (int v = 0; v < V; ++v)
            val[v] = val[v] > 0.f ? val[v] : (__expf(val[v]) - 1.f);
        // V==4: 4 bf16 hi + 4 bf16 lo per lane, 8B stores
        unsigned int hpk[2], lpk[2];
#pragma unroll
        for (int q = 0; q < 2; ++q) {
            unsigned short h0 = f2bf(val[2 * q]), h1 = f2bf(val[2 * q + 1]);
            unsigned short l0 = f2bf(val[2 * q] - bf2f(h0));
            unsigned short l1 = f2bf(val[2 * q + 1] - bf2f(h1));
            hpk[q] = (unsigned int)h0 | ((unsigned int)h1 << 16);
            lpk[q] = (unsigned int)l0 | ((unsigned int)l1 << 16);
        }
        *reinterpret_cast<uint2*>(ohi + (size_t)wid * F + f0) = make_uint2(hpk[0], hpk[1]);
        *reinterpret_cast<uint2*>(olo + (size_t)wid * F + f0) = make_uint2(lpk[0], lpk[1]);
    } else {
        // head-mean over lanes {b, b+8, b+16, b+24} (b = hl&7), same tree as r12
#pragma unroll
        for (int v = 0; v < V; ++v) {
            val[v] += __shfl_xor(val[v], 8);
            val[v] += __shfl_xor(val[v], 16);
        }
        if (hl < 8) {
            float4 o0 = make_float4(val[0] * 0.25f, val[1] * 0.25f, val[2] * 0.25f, val[3] * 0.25f);
            float4 o1 = make_float4(val[4] * 0.25f, val[5] * 0.25f, val[6] * 0.25f, val[7] * 0.25f);
            *reinterpret_cast<float4*>(out + (size_t)wid * D + hl * 8) = o0;
            *reinterpret_cast<float4*>(out + (size_t)wid * D + hl * 8 + 4) = o1;
        }
    }
}

// ---------------------------------------------------------------- launch
extern "C" void kernel_launch(void* const* d_in, const int* in_sizes, int n_in,
                              void* d_out, int out_size, void* d_ws, size_t ws_size,
                              hipStream_t stream) {
    const float* nfeat = (const float*)d_in[0];
    const int* src = (const int*)d_in[1];
    const int* dst = (const int*)d_in[2];
    const float* W0 = (const float*)d_in[3];
    const float* al0 = (const float*)d_in[4];
    const float* ar0 = (const float*)d_in[5];
    const float* b0 = (const float*)d_in[6];
    const float* W1 = (const float*)d_in[7];
    const float* al1 = (const float*)d_in[8];
    const float* ar1 = (const float*)d_in[9];
    const float* b1 = (const float*)d_in[10];
    const float* W2 = (const float*)d_in[11];
    const float* al2 = (const float*)d_in[12];
    const float* ar2 = (const float*)d_in[13];
    const float* b2 = (const float*)d_in[14];
    float* out = (float*)d_out;

    char* w = (char*)d_ws;
    unsigned short* XA_hi = (unsigned short*)w; w += (size_t)N_NODES * 128 * 2;  // 25.6MB
    unsigned short* XA_lo = (unsigned short*)w; w += (size_t)N_NODES * 128 * 2;
    unsigned short* XB_hi = (unsigned short*)w; w += (size_t)N_NODES * 128 * 2;
    unsigned short* XB_lo = (unsigned short*)w; w += (size_t)N_NODES * 128 * 2;
    _Float16* Ph01 = (_Float16*)w; w += (size_t)N_NODES * 128 * 2;               // 25.6MB
    float* el = (float*)w;     w += (size_t)N_NODES * 4 * 4;
    float* er = (float*)w;     w += (size_t)N_NODES * 4 * 4;
    int* rowptr = (int*)w;     w += (size_t)(N_NODES + 4) * 4;
    int* deg = (int*)w;        w += (size_t)N_NODES * 4;
    int* bsum = (int*)w;       w += 256 * 4;
    int* csr_src = (int*)w;    w += (size_t)N_EDGES * 4;
    unsigned short* Wt0h = (unsigned short*)w; w += 16384 * 2;
    unsigned short* Wt0l = (unsigned short*)w; w += 16384 * 2;
    unsigned short* Wt1h = (unsigned short*)w; w += 16384 * 2;
    unsigned short* Wt1l = (unsigned short*)w; w += 16384 * 2;
    unsigned short* Wt2h = (unsigned short*)w; w += 32768 * 2;
    unsigned short* Wt2l = (unsigned short*)w; w += 32768 * 2;

    // Aliases (lifetime-checked):
    _Float16* H2h = (_Float16*)XB_hi; // 51.2MB spans XB_hi+XB_lo (dead at GEMM2)

    const int nb_scan = (N_NODES + 1023) / 1024;

    // ---- W converts (single launch)
    convert_w_all_kernel<<<256, 256, 0, stream>>>(W0, W1, W2, Wt0h, Wt0l, Wt1h, Wt1l,
                                                  Wt2h, Wt2l);

    // ---- CSR build (bucketed scatter: write window per-XCD-L2-resident)
    hipMemsetAsync(deg, 0, (size_t)N_NODES * 4, stream);
    hist_kernel<<<(N_EDGES + 255) / 256, 256, 0, stream>>>(dst, deg);
    scan_block_kernel<<<nb_scan, 256, 0, stream>>>(deg, rowptr, bsum);
    scan_bsum_kernel<<<1, 128, 0, stream>>>(bsum, nb_scan);
    scan_add_kernel<<<(N_NODES + 256) / 256, 256, 0, stream>>>(rowptr, bsum);
    hipMemsetAsync(deg, 0, (size_t)N_NODES * 4, stream);
    {
        const int eb = (N_EDGES + 255) / 256;
        const int rs = (N_NODES + NPASS - 1) / NPASS;
        for (int p = 0; p < NPASS; ++p)
            scatter_pass_kernel<<<eb, 256, 0, stream>>>(src, dst, rowptr, deg, csr_src,
                                                        p * rs, min((p + 1) * rs, N_NODES));
    }

    const int ng_blocks = (N_NODES + 7) / 8;      // 2 nodes per wave
    dim3 gg1(782, 1), gg2(782, 2);

    // ---- Layer 0 (GEMM stages fp32 nfeat; fuses el/er + fp16 h)
    mfma_gemm_kernel<32, true><<<gg1, 256, 0, stream>>>(nullptr, nullptr, nfeat, Wt0h, Wt0l,
                                                        el, er, Ph01, N_NODES, 128, al0, ar0);
    sgather2_kernel<128, 0><<<ng_blocks, 256, 0, stream>>>(Ph01, el, er, rowptr, csr_src, b0,
                                                           nullptr, XB_hi, XB_lo);

    // ---- Layer 1
    mfma_gemm_kernel<32, false><<<gg1, 256, 0, stream>>>(XB_hi, XB_lo, nullptr, Wt1h, Wt1l,
                                                         el, er, Ph01, N_NODES, 128, al1, ar1);
    sgather2_kernel<128, 0><<<ng_blocks, 256, 0, stream>>>(Ph01, el, er, rowptr, csr_src, b1,
                                                           nullptr, XA_hi, XA_lo);

    // ---- Layer 2
    mfma_gemm_kernel<64, false><<<gg2, 256, 0, stream>>>(XA_hi, XA_lo, nullptr, Wt2h, Wt2l,
                                                         el, er, H2h, N_NODES, 256, al2, ar2);
    sgather2_kernel<256, 1><<<ng_blocks, 256, 0, stream>>>(H2h, el, er, rowptr, csr_src, b2,
                                                           out, nullptr, nullptr);
}

// Round 14
// 648.574 us; speedup vs baseline: 1.0450x; 1.0450x over previous
//
#include <hip/hip_runtime.h>
#include <hip/hip_bf16.h>
#include <cstddef>
#include <cstdint>

#define N_NODES 100000
#define N_EDGES 1600000
#define NPASS 2

typedef __attribute__((ext_vector_type(8))) short bf16x8;
typedef __attribute__((ext_vector_type(4))) float f32x4;
typedef __attribute__((ext_vector_type(2))) _Float16 half2_t;
typedef __attribute__((ext_vector_type(4))) _Float16 half4_t;
typedef __attribute__((ext_vector_type(8))) _Float16 half8_t;

__device__ inline unsigned short f2bf(float x) {
    unsigned int u = __float_as_uint(x);
    unsigned int r = (u + 0x7fffu + ((u >> 16) & 1u)) >> 16;
    return (unsigned short)r;
}
__device__ inline float bf2f(unsigned short b) {
    return __uint_as_float((unsigned int)b << 16);
}
__device__ inline unsigned short f2h_bits(float x) {
    _Float16 h = (_Float16)x;
    return __builtin_bit_cast(unsigned short, h);
}

// ---------------------------------------------------------------- CSR build
__global__ void hist_kernel(const int* __restrict__ dst, int* __restrict__ deg) {
    int e = blockIdx.x * 256 + threadIdx.x;
    if (e < N_EDGES) atomicAdd(&deg[dst[e]], 1);
}

__global__ void scan_block_kernel(const int* __restrict__ deg, int* __restrict__ rowptr,
                                  int* __restrict__ bsum) {
    __shared__ int s[256];
    int t = threadIdx.x;
    int base = blockIdx.x * 1024 + t * 4;
    int v[4]; int sum = 0;
#pragma unroll
    for (int j = 0; j < 4; ++j) { v[j] = (base + j < N_NODES) ? deg[base + j] : 0; sum += v[j]; }
    s[t] = sum; __syncthreads();
    for (int off = 1; off < 256; off <<= 1) {
        int x = (t >= off) ? s[t - off] : 0;
        __syncthreads();
        s[t] += x;
        __syncthreads();
    }
    int excl = (t > 0) ? s[t - 1] : 0;
    if (t == 255) bsum[blockIdx.x] = s[255];
    int run = excl;
#pragma unroll
    for (int j = 0; j < 4; ++j) { if (base + j < N_NODES) rowptr[base + j] = run; run += v[j]; }
}

__global__ void scan_bsum_kernel(int* bsum, int nb) {
    __shared__ int s[128];
    int t = threadIdx.x;
    int v = (t < nb) ? bsum[t] : 0;
    s[t] = v; __syncthreads();
    for (int off = 1; off < 128; off <<= 1) {
        int x = (t >= off) ? s[t - off] : 0;
        __syncthreads();
        s[t] += x;
        __syncthreads();
    }
    if (t < nb) bsum[t] = (t > 0) ? s[t - 1] : 0;
}

__global__ void scan_add_kernel(int* __restrict__ rowptr, const int* __restrict__ bsum) {
    int i = blockIdx.x * 256 + threadIdx.x;
    if (i < N_NODES) rowptr[i] += bsum[i >> 10];
    if (i == 0) rowptr[N_NODES] = N_EDGES;
}

// Bucketed scatter: write window (csr slab + fill slice) is L2-resident per pass.
__global__ __launch_bounds__(256) void scatter_pass_kernel(
    const int* __restrict__ src, const int* __restrict__ dst,
    const int* __restrict__ rowptr, int* __restrict__ fill,
    int* __restrict__ csr_src, int lo, int hi) {
    int e = blockIdx.x * 256 + threadIdx.x;
    if (e >= N_EDGES) return;
    int d = dst[e];
    if (d >= lo && d < hi) {
        int pos = rowptr[d] + atomicAdd(&fill[d], 1);
        csr_src[pos] = src[e];
    }
}

// ---------------------------------------------------------------- W converts (all 3, one launch)
__global__ __launch_bounds__(256) void convert_w_all_kernel(
    const float* __restrict__ W0, const float* __restrict__ W1, const float* __restrict__ W2,
    unsigned short* __restrict__ Wt0h, unsigned short* __restrict__ Wt0l,
    unsigned short* __restrict__ Wt1h, unsigned short* __restrict__ Wt1l,
    unsigned short* __restrict__ Wt2h, unsigned short* __restrict__ Wt2l) {
    int t = blockIdx.x * 256 + threadIdx.x;
    const float* W; unsigned short* Wh; unsigned short* Wl; int Ncols; int i;
    if (t < 16384)      { W = W0; Wh = Wt0h; Wl = Wt0l; Ncols = 128; i = t; }
    else if (t < 32768) { W = W1; Wh = Wt1h; Wl = Wt1l; Ncols = 128; i = t - 16384; }
    else                { W = W2; Wh = Wt2h; Wl = Wt2l; Ncols = 256; i = t - 32768; }
    int n = i >> 7, k = i & 127;
    float x = W[(size_t)k * Ncols + n];
    unsigned short h = f2bf(x);
    unsigned short l = f2bf(x - bf2f(h));
    Wh[i] = h;
    Wl[i] = l;
}

// ---------------------------------------------------------------- MFMA split-bf16 GEMM
// FP32IN: stage raw fp32 X, split to bf16 hi/lo during staging (layer 0).
// Fused epilogue: el/er from fp32 acc (16-lane butterfly) + fp16 h via LDS repack.
template <int DHEAD, bool FP32IN>
__global__ __launch_bounds__(256) void mfma_gemm_kernel(
    const unsigned short* __restrict__ Xhi, const unsigned short* __restrict__ Xlo,
    const float* __restrict__ Xf,
    const unsigned short* __restrict__ Wth, const unsigned short* __restrict__ Wtl,
    float* __restrict__ el, float* __restrict__ er, _Float16* __restrict__ Hh,
    int M, int ldH, const float* __restrict__ alv, const float* __restrict__ arv) {
    __shared__ unsigned short AH[128 * 136];
    __shared__ unsigned short AL[128 * 136];
    const int tid = threadIdx.x;
    const int wave = tid >> 6, lane = tid & 63;
    const int r = lane & 15, kg = lane >> 4;
    const int row0 = blockIdx.x * 128;
    const int col0 = blockIdx.y * 128;

    if constexpr (FP32IN) {
#pragma unroll
        for (int i = 0; i < 16; ++i) {
            int idx = i * 256 + tid;
            int rr = idx >> 5;
            int u = idx & 31;
            int grow = row0 + rr;
            if (grow > M - 1) grow = M - 1;
            float4 v = *reinterpret_cast<const float4*>(Xf + (size_t)grow * 128 + u * 4);
            unsigned short h0 = f2bf(v.x), h1 = f2bf(v.y), h2 = f2bf(v.z), h3 = f2bf(v.w);
            unsigned short l0 = f2bf(v.x - bf2f(h0)), l1 = f2bf(v.y - bf2f(h1));
            unsigned short l2 = f2bf(v.z - bf2f(h2)), l3 = f2bf(v.w - bf2f(h3));
            unsigned int* hp = reinterpret_cast<unsigned int*>(&AH[rr * 136 + u * 4]);
            hp[0] = (unsigned int)h0 | ((unsigned int)h1 << 16);
            hp[1] = (unsigned int)h2 | ((unsigned int)h3 << 16);
            unsigned int* lp = reinterpret_cast<unsigned int*>(&AL[rr * 136 + u * 4]);
            lp[0] = (unsigned int)l0 | ((unsigned int)l1 << 16);
            lp[1] = (unsigned int)l2 | ((unsigned int)l3 << 16);
        }
    } else {
#pragma unroll
        for (int i = 0; i < 16; ++i) {
            int sa = i * 256 + tid;
            int a = sa >> 11;
            int s = sa & 2047;
            int rr = s >> 4;
            int u = s & 15;
            const unsigned short* srcp = (a ? Xlo : Xhi) + (size_t)(row0 + rr) * 128 + u * 8;
            unsigned short* dstp = (a ? AL : AH) + rr * 136 + u * 8;
            *reinterpret_cast<uint4*>(dstp) = *reinterpret_cast<const uint4*>(srcp);
        }
    }
    __syncthreads();

    f32x4 acc[2][8];
#pragma unroll
    for (int rt = 0; rt < 2; ++rt)
#pragma unroll
        for (int ct = 0; ct < 8; ++ct)
            acc[rt][ct] = (f32x4){0.f, 0.f, 0.f, 0.f};

#pragma unroll
    for (int ks = 0; ks < 4; ++ks) {
        bf16x8 bh[8], bl[8];
#pragma unroll
        for (int ct = 0; ct < 8; ++ct) {
            size_t off = (size_t)(col0 + ct * 16 + r) * 128 + ks * 32 + kg * 8;
            bh[ct] = *reinterpret_cast<const bf16x8*>(Wth + off);
            bl[ct] = *reinterpret_cast<const bf16x8*>(Wtl + off);
        }
#pragma unroll
        for (int rt = 0; rt < 2; ++rt) {
            int lrow = wave * 32 + rt * 16 + r;
            bf16x8 ah = *reinterpret_cast<const bf16x8*>(&AH[lrow * 136 + ks * 32 + kg * 8]);
            bf16x8 al8 = *reinterpret_cast<const bf16x8*>(&AL[lrow * 136 + ks * 32 + kg * 8]);
#pragma unroll
            for (int ct = 0; ct < 8; ++ct) {
                acc[rt][ct] = __builtin_amdgcn_mfma_f32_16x16x32_bf16(ah, bh[ct], acc[rt][ct], 0, 0, 0);
                acc[rt][ct] = __builtin_amdgcn_mfma_f32_16x16x32_bf16(al8, bh[ct], acc[rt][ct], 0, 0, 0);
                acc[rt][ct] = __builtin_amdgcn_mfma_f32_16x16x32_bf16(ah, bl[ct], acc[rt][ct], 0, 0, 0);
            }
        }
    }

    // ---- epilogue 1: el/er
    constexpr int CTH = DHEAD / 16;
    constexpr int HB = 8 / CTH;
    float als[8], ars[8];
#pragma unroll
    for (int ct = 0; ct < 8; ++ct) {
        als[ct] = alv[col0 + ct * 16 + r];
        ars[ct] = arv[col0 + ct * 16 + r];
    }
    f32x4 pel[2][HB], per_[2][HB];
#pragma unroll
    for (int rt = 0; rt < 2; ++rt)
#pragma unroll
        for (int hl = 0; hl < HB; ++hl) {
            pel[rt][hl] = (f32x4){0.f, 0.f, 0.f, 0.f};
            per_[rt][hl] = (f32x4){0.f, 0.f, 0.f, 0.f};
        }
#pragma unroll
    for (int rt = 0; rt < 2; ++rt)
#pragma unroll
        for (int ct = 0; ct < 8; ++ct) {
            pel[rt][ct / CTH] += acc[rt][ct] * als[ct];
            per_[rt][ct / CTH] += acc[rt][ct] * ars[ct];
        }
#pragma unroll
    for (int off = 1; off < 16; off <<= 1) {
#pragma unroll
        for (int rt = 0; rt < 2; ++rt)
#pragma unroll
            for (int hl = 0; hl < HB; ++hl)
#pragma unroll
                for (int j = 0; j < 4; ++j) {
                    pel[rt][hl][j] += __shfl_xor(pel[rt][hl][j], off);
                    per_[rt][hl][j] += __shfl_xor(per_[rt][hl][j], off);
                }
    }
#pragma unroll
    for (int hl = 0; hl < HB; ++hl) {
        if (r == hl) {
            int hg = col0 / DHEAD + hl;
#pragma unroll
            for (int rt = 0; rt < 2; ++rt)
#pragma unroll
                for (int j = 0; j < 4; ++j) {
                    int grow = row0 + wave * 32 + rt * 16 + kg * 4 + j;
                    if (grow < M) {
                        el[(size_t)grow * 4 + hg] = pel[rt][hl][j];
                        er[(size_t)grow * 4 + hg] = per_[rt][hl][j];
                    }
                }
        }
    }

    // ---- epilogue 2: fp16 h via LDS repack
    __syncthreads();
#pragma unroll
    for (int rt = 0; rt < 2; ++rt)
#pragma unroll
        for (int ct = 0; ct < 8; ++ct)
#pragma unroll
            for (int j = 0; j < 4; ++j) {
                int lrow = wave * 32 + rt * 16 + kg * 4 + j;
                AH[lrow * 136 + ct * 16 + r] = f2h_bits(acc[rt][ct][j]);
            }
    __syncthreads();
#pragma unroll
    for (int it = 0; it < 8; ++it) {
        int idx = it * 256 + tid;
        int rr = idx >> 4;
        int c8 = idx & 15;
        int grow = row0 + rr;
        if (grow < M)
            *reinterpret_cast<uint4*>(Hh + (size_t)grow * ldH + col0 + c8 * 8) =
                *reinterpret_cast<const uint4*>(&AH[rr * 136 + c8 * 8]);
    }
}

// ---------------------------------------------------------------- fused softmax+gather
// TWO NODES PER WAVE (half-wave = one node, 32 lanes). Lane hl owns V=F/32
// consecutive feats (8B half4 for F=128, 16B half8 for F=256); head hh=hl>>3.
// BIT-IDENTICAL summation to the round-7 kernel (chunk=32 multiple of 4).
// Compiler memory fences around the wsh write prevent LDS write/read reordering.
// MODE 0: elu -> bf16 hi/lo [N,F].  MODE 1: head-mean -> out[N,F/4] fp32.
template <int F, int MODE>
__global__ __launch_bounds__(256) void sgather2_kernel(
    const _Float16* __restrict__ hfeat, const float* __restrict__ el,
    const float* __restrict__ er, const int* __restrict__ rowptr,
    const int* __restrict__ csr_src, const float* __restrict__ bias,
    float* __restrict__ out, unsigned short* __restrict__ ohi,
    unsigned short* __restrict__ olo) {
    constexpr int V = F / 32;             // 4 (F=128) or 8 (F=256)
    constexpr int D = F / 4;
    __shared__ float wsh[4][2][128];
    int wv = threadIdx.x >> 6;
    int lane = threadIdx.x & 63;
    int hw = lane >> 5;                   // which half-wave (node select)
    int hl = lane & 31;                   // lane within half-wave
    int wid = blockIdx.x * 8 + (threadIdx.x >> 5);
    if (wid >= N_NODES) return;
    int row0 = rowptr[wid], row1 = rowptr[wid + 1];
    int f0 = hl * V;
    int hh = hl >> 3;                     // = f0 / D for both F=128,256
    float4 ern = *reinterpret_cast<const float4*>(er + (size_t)wid * 4);

    float ac0[V], ac1[V], ac2[V], ac3[V];
#pragma unroll
    for (int v = 0; v < V; ++v) { ac0[v] = 0.f; ac1[v] = 0.f; ac2[v] = 0.f; ac3[v] = 0.f; }
    float den = 0.f;

    for (int base = row0; base < row1; base += 32) {
        int i = base + hl;
        int sv = (i < row1) ? csr_src[i] : 0;
        float4 e4 = *reinterpret_cast<const float4*>(el + (size_t)sv * 4);
        float4 es;
        es.x = e4.x + ern.x; es.x = es.x > 0.f ? es.x : 0.2f * es.x; es.x = __expf(es.x);
        es.y = e4.y + ern.y; es.y = es.y > 0.f ? es.y : 0.2f * es.y; es.y = __expf(es.y);
        es.z = e4.z + ern.z; es.z = es.z > 0.f ? es.z : 0.2f * es.z; es.z = __expf(es.z);
        es.w = e4.w + ern.w; es.w = es.w > 0.f ? es.w : 0.2f * es.w; es.w = __expf(es.w);
        asm volatile("" ::: "memory");    // fence: keep prior reads before the write
        *reinterpret_cast<float4*>(&wsh[wv][hw][hl * 4]) = es;
        asm volatile("" ::: "memory");    // fence: keep the write before the reads
        // same-wave LDS: HW executes the wave's DS ops in program order

        int cnt = min(32, row1 - base);
        const float* wp = &wsh[wv][hw][hh];
        int j = 0;
        for (; j + 4 <= cnt; j += 4) {
            int s0 = __shfl(sv, j, 32), s1 = __shfl(sv, j + 1, 32);
            int s2 = __shfl(sv, j + 2, 32), s3 = __shfl(sv, j + 3, 32);
            float w0 = wp[(j + 0) * 4], w1 = wp[(j + 1) * 4];
            float w2 = wp[(j + 2) * 4], w3 = wp[(j + 3) * 4];
            den += (w0 + w1) + (w2 + w3);
            if (V == 8) {
                half8_t a = *reinterpret_cast<const half8_t*>(hfeat + (size_t)s0 * F + f0);
                half8_t b = *reinterpret_cast<const half8_t*>(hfeat + (size_t)s1 * F + f0);
                half8_t c = *reinterpret_cast<const half8_t*>(hfeat + (size_t)s2 * F + f0);
                half8_t d = *reinterpret_cast<const half8_t*>(hfeat + (size_t)s3 * F + f0);
#pragma unroll
                for (int v = 0; v < V; ++v) {
                    ac0[v] = fmaf(w0, (float)a[v], ac0[v]);
                    ac1[v] = fmaf(w1, (float)b[v], ac1[v]);
                    ac2[v] = fmaf(w2, (float)c[v], ac2[v]);
                    ac3[v] = fmaf(w3, (float)d[v], ac3[v]);
                }
            } else {
                half4_t a = *reinterpret_cast<const half4_t*>(hfeat + (size_t)s0 * F + f0);
                half4_t b = *reinterpret_cast<const half4_t*>(hfeat + (size_t)s1 * F + f0);
                half4_t c = *reinterpret_cast<const half4_t*>(hfeat + (size_t)s2 * F + f0);
                half4_t d = *reinterpret_cast<const half4_t*>(hfeat + (size_t)s3 * F + f0);
#pragma unroll
                for (int v = 0; v < V; ++v) {
                    ac0[v] = fmaf(w0, (float)a[v], ac0[v]);
                    ac1[v] = fmaf(w1, (float)b[v], ac1[v]);
                    ac2[v] = fmaf(w2, (float)c[v], ac2[v]);
                    ac3[v] = fmaf(w3, (float)d[v], ac3[v]);
                }
            }
        }
        for (; j < cnt; ++j) {
            int s0 = __shfl(sv, j, 32);
            float w0 = wp[(size_t)j * 4];
            den += w0;
            if (V == 8) {
                half8_t a = *reinterpret_cast<const half8_t*>(hfeat + (size_t)s0 * F + f0);
#pragma unroll
                for (int v = 0; v < V; ++v) ac0[v] = fmaf(w0, (float)a[v], ac0[v]);
            } else {
                half4_t a = *reinterpret_cast<const half4_t*>(hfeat + (size_t)s0 * F + f0);
#pragma unroll
                for (int v = 0; v < V; ++v) ac0[v] = fmaf(w0, (float)a[v], ac0[v]);
            }
        }
        asm volatile("" ::: "memory");    // fence: next chunk's write stays after these reads
    }

    float inv = den > 0.f ? 1.f / den : 0.f;
    float val[V];
#pragma unroll
    for (int v = 0; v < V; ++v)
        val[v] = ((ac0[v] + ac1[v]) + (ac2[v] + ac3[v])) * inv + bias[f0 + v];

    if (MODE == 0) {
#pragma unroll
        for (int v = 0; v < V; ++v)
            val[v] = val[v] > 0.f ? val[v] : (__expf(val[v]) - 1.f);
        // V==4: 4 bf16 hi + 4 bf16 lo per lane, 8B stores
        unsigned int hpk[2], lpk[2];
#pragma unroll
        for (int q = 0; q < 2; ++q) {
            unsigned short h0 = f2bf(val[2 * q]), h1 = f2bf(val[2 * q + 1]);
            unsigned short l0 = f2bf(val[2 * q] - bf2f(h0));
            unsigned short l1 = f2bf(val[2 * q + 1] - bf2f(h1));
            hpk[q] = (unsigned int)h0 | ((unsigned int)h1 << 16);
            lpk[q] = (unsigned int)l0 | ((unsigned int)l1 << 16);
        }
        *reinterpret_cast<uint2*>(ohi + (size_t)wid * F + f0) = make_uint2(hpk[0], hpk[1]);
        *reinterpret_cast<uint2*>(olo + (size_t)wid * F + f0) = make_uint2(lpk[0], lpk[1]);
    } else {
        // head-mean over lanes {b, b+8, b+16, b+24} (b = hl&7), same tree as r7
#pragma unroll
        for (int v = 0; v < V; ++v) {
            val[v] += __shfl_xor(val[v], 8);
            val[v] += __shfl_xor(val[v], 16);
        }
        if (hl < 8) {
            float4 o0 = make_float4(val[0] * 0.25f, val[1] * 0.25f, val[2] * 0.25f, val[3] * 0.25f);
            float4 o1 = make_float4(val[4] * 0.25f, val[5] * 0.25f, val[6] * 0.25f, val[7] * 0.25f);
            *reinterpret_cast<float4*>(out + (size_t)wid * D + hl * 8) = o0;
            *reinterpret_cast<float4*>(out + (size_t)wid * D + hl * 8 + 4) = o1;
        }
    }
}

// ---------------------------------------------------------------- launch
extern "C" void kernel_launch(void* const* d_in, const int* in_sizes, int n_in,
                              void* d_out, int out_size, void* d_ws, size_t ws_size,
                              hipStream_t stream) {
    const float* nfeat = (const float*)d_in[0];
    const int* src = (const int*)d_in[1];
    const int* dst = (const int*)d_in[2];
    const float* W0 = (const float*)d_in[3];
    const float* al0 = (const float*)d_in[4];
    const float* ar0 = (const float*)d_in[5];
    const float* b0 = (const float*)d_in[6];
    const float* W1 = (const float*)d_in[7];
    const float* al1 = (const float*)d_in[8];
    const float* ar1 = (const float*)d_in[9];
    const float* b1 = (const float*)d_in[10];
    const float* W2 = (const float*)d_in[11];
    const float* al2 = (const float*)d_in[12];
    const float* ar2 = (const float*)d_in[13];
    const float* b2 = (const float*)d_in[14];
    float* out = (float*)d_out;

    char* w = (char*)d_ws;
    unsigned short* XA_hi = (unsigned short*)w; w += (size_t)N_NODES * 128 * 2;  // 25.6MB
    unsigned short* XA_lo = (unsigned short*)w; w += (size_t)N_NODES * 128 * 2;
    unsigned short* XB_hi = (unsigned short*)w; w += (size_t)N_NODES * 128 * 2;
    unsigned short* XB_lo = (unsigned short*)w; w += (size_t)N_NODES * 128 * 2;
    _Float16* Ph01 = (_Float16*)w; w += (size_t)N_NODES * 128 * 2;               // 25.6MB
    float* el = (float*)w;     w += (size_t)N_NODES * 4 * 4;
    float* er = (float*)w;     w += (size_t)N_NODES * 4 * 4;
    int* rowptr = (int*)w;     w += (size_t)(N_NODES + 4) * 4;
    int* deg = (int*)w;        w += (size_t)N_NODES * 4;      // deg + fill zeroed together
    int* fill = (int*)w;       w += (size_t)N_NODES * 4;
    int* bsum = (int*)w;       w += 256 * 4;
    int* csr_src = (int*)w;    w += (size_t)N_EDGES * 4;
    unsigned short* Wt0h = (unsigned short*)w; w += 16384 * 2;
    unsigned short* Wt0l = (unsigned short*)w; w += 16384 * 2;
    unsigned short* Wt1h = (unsigned short*)w; w += 16384 * 2;
    unsigned short* Wt1l = (unsigned short*)w; w += 16384 * 2;
    unsigned short* Wt2h = (unsigned short*)w; w += 32768 * 2;
    unsigned short* Wt2l = (unsigned short*)w; w += 32768 * 2;

    // Aliases (lifetime-checked):
    _Float16* H2h = (_Float16*)XB_hi; // 51.2MB spans XB_hi+XB_lo (dead at GEMM2)

    const int nb_scan = (N_NODES + 1023) / 1024;

    // ---- W converts (single launch)
    convert_w_all_kernel<<<256, 256, 0, stream>>>(W0, W1, W2, Wt0h, Wt0l, Wt1h, Wt1l,
                                                  Wt2h, Wt2l);

    // ---- CSR build (bucketed scatter; deg+fill zeroed in ONE memset)
    hipMemsetAsync(deg, 0, (size_t)N_NODES * 8, stream);
    hist_kernel<<<(N_EDGES + 255) / 256, 256, 0, stream>>>(dst, deg);
    scan_block_kernel<<<nb_scan, 256, 0, stream>>>(deg, rowptr, bsum);
    scan_bsum_kernel<<<1, 128, 0, stream>>>(bsum, nb_scan);
    scan_add_kernel<<<(N_NODES + 256) / 256, 256, 0, stream>>>(rowptr, bsum);
    {
        const int eb = (N_EDGES + 255) / 256;
        const int rs = (N_NODES + NPASS - 1) / NPASS;
        for (int p = 0; p < NPASS; ++p)
            scatter_pass_kernel<<<eb, 256, 0, stream>>>(src, dst, rowptr, fill, csr_src,
                                                        p * rs, min((p + 1) * rs, N_NODES));
    }

    const int ng_blocks = (N_NODES + 7) / 8;      // 2 nodes per wave
    dim3 gg1(782, 1), gg2(782, 2);

    // ---- Layer 0 (GEMM stages fp32 nfeat; fuses el/er + fp16 h)
    mfma_gemm_kernel<32, true><<<gg1, 256, 0, stream>>>(nullptr, nullptr, nfeat, Wt0h, Wt0l,
                                                        el, er, Ph01, N_NODES, 128, al0, ar0);
    sgather2_kernel<128, 0><<<ng_blocks, 256, 0, stream>>>(Ph01, el, er, rowptr, csr_src, b0,
                                                           nullptr, XB_hi, XB_lo);

    // ---- Layer 1
    mfma_gemm_kernel<32, false><<<gg1, 256, 0, stream>>>(XB_hi, XB_lo, nullptr, Wt1h, Wt1l,
                                                         el, er, Ph01, N_NODES, 128, al1, ar1);
    sgather2_kernel<128, 0><<<ng_blocks, 256, 0, stream>>>(Ph01, el, er, rowptr, csr_src, b1,
                                                           nullptr, XA_hi, XA_lo);

    // ---- Layer 2
    mfma_gemm_kernel<64, false><<<gg2, 256, 0, stream>>>(XA_hi, XA_lo, nullptr, Wt2h, Wt2l,
                                                         el, er, H2h, N_NODES, 256, al2, ar2);
    sgather2_kernel<256, 1><<<ng_blocks, 256, 0, stream>>>(H2h, el, er, rowptr, csr_src, b2,
                                                           out, nullptr, nullptr);
}